// Round 9
// baseline (246.206 us; speedup 1.0000x reference)
//
#include <hip/hip_runtime.h>
#include <hip/hip_bf16.h>

#define TB 512

// B=32, R=2, T=128, N=128, C_IN=64, C_OUT=64
constexpr size_t XOUT_ELEMS = 32ull * 64 * 128 * 128;  // 33,554,432

typedef short bf16x8  __attribute__((ext_vector_type(8)));
typedef short short4v __attribute__((ext_vector_type(4)));
typedef float f32x4   __attribute__((ext_vector_type(4)));

static __device__ __forceinline__ short f2bf(float f) {
    __hip_bfloat16 hb = __float2bfloat16(f);           // RNE
    return *reinterpret_cast<short*>(&hb);
}

// lgkm-only barrier: publishes LDS writes/reads without draining vmcnt
// (measured neutral vs __syncthreads in R8, kept as harmless).
static __device__ __forceinline__ void lgkm_barrier() {
    asm volatile("s_waitcnt lgkmcnt(0)" ::: "memory");
    __builtin_amdgcn_s_barrier();
    asm volatile("" ::: "memory");
}

// LDS byte map (81920 B = 2 blocks/CU of the 160 KiB pool):
//  [0,16384)      shXT: x^T bf16, row n stride 128B; elem (n,c): n*128 + po*16 + (c&7)*2,
//                 po = (c>>3) ^ ((n>>2)&7).   Dead after P1; [0,512) reused as dd[128] f32.
//  [16384,49152)  yt: y[o][m] bf16 (read-only after P1), row o stride 256B;
//                 elem: 16384 + o*256 + po*16 + (m&7)*2, po = (m>>3) ^ (o&7)
//  [49152,81920)  P0/P1: shW bf16 [o][c], row o stride 128B; elem: o*128 + po*16 + (c&7)*2,
//                 po = (c>>3) ^ (o&7).
//                 Relation loop: shAT = d[m]*(A+I)[m][n] bf16 transposed (row n, col m);
//                 elem: 49152 + n*256 + po*16 + (m&7)*2, po = (m>>3) ^ ((n>>2)&7)

__global__ __launch_bounds__(TB, 4)
void gcn_fused(const float* __restrict__ xg, const float* __restrict__ Ag,
               const float* __restrict__ Wg, const float* __restrict__ bg,
               float* __restrict__ outg)
{
    __shared__ float4 smem4[5120];
    char*  smem = (char*)smem4;
    float* dd   = (float*)smem;   // d[m] per relation

    const int tid = threadIdx.x;
    const int w   = tid >> 6;     // wave 0..7
    const int l   = tid & 63;
    const int g   = l >> 5;
    const int h   = l & 31;
    const int l15 = l & 15;
    const int l4  = l >> 4;       // 0..3

    const int blk = blockIdx.x;
    const int b = blk >> 7, t = blk & 127;

    // ---------------- P0a: stage x^T (bf16, swizzled); PLAIN loads (L3-allocate) ----------------
    {
        float vv[4][4];
        #pragma unroll
        for (int i = 0; i < 4; ++i) {
            int c = 8*w + 4*g + i;
            f32x4 v = *(const f32x4*)(xg + ((size_t)(b*64 + c)*128 + t)*128 + 4*h);
            vv[i][0] = v[0]; vv[i][1] = v[1]; vv[i][2] = v[2]; vv[i][3] = v[3];
        }
        int po = w ^ (h & 7);                       // c-oct = w ; key = (n>>2)&7 = h&7
        #pragma unroll
        for (int e = 0; e < 4; ++e) {
            int n = 4*h + e;
            short4v pk;
            pk[0] = f2bf(vv[0][e]); pk[1] = f2bf(vv[1][e]);
            pk[2] = f2bf(vv[2][e]); pk[3] = f2bf(vv[3][e]);
            *(short4v*)(smem + n*128 + po*16 + 8*g) = pk;
        }
    }
    // ---------------- P0b: stage W -> shW bf16 (coalesced, cached loads) ----------------
    #pragma unroll
    for (int k2 = 0; k2 < 4; ++k2) {
        int q = tid + TB*k2;                        // < 2048 float4 chunks of W
        f32x4 v = ((const f32x4*)Wg)[q];
        int o = q >> 4, oct = (q >> 1) & 7, hf = q & 1;
        short4v pk;
        pk[0] = f2bf(v[0]); pk[1] = f2bf(v[1]); pk[2] = f2bf(v[2]); pk[3] = f2bf(v[3]);
        *(short4v*)(smem + 49152 + o*128 + (oct ^ (o & 7))*16 + hf*8) = pk;
    }
    // ---------------- P0c: bias per D-column (o = 16*ot + l15) ----------------
    float bia[8];
    #pragma unroll
    for (int ot = 0; ot < 8; ++ot) bia[ot] = bg[16*ot + l15];
    lgkm_barrier();

    // ---------------- P1: GEMM1, swapped operands: D[n][o] = xT·W^T ----------------
    {
        const int n    = 16*w + l15;
        const int keyx = (n >> 2) & 7;
        bf16x8 af0 = *(const bf16x8*)(smem + n*128 + ((0 + l4) ^ keyx)*16);
        bf16x8 af1 = *(const bf16x8*)(smem + n*128 + ((4 + l4) ^ keyx)*16);
        const int m0   = 16*w + 4*l4;               // D row base (m = n-axis of yt)
        const int pob  = m0 >> 3;                   // = 2w + (l4>>1)
        const int keyw = l15 & 7;                   // o & 7
        #pragma unroll
        for (int ot = 0; ot < 8; ++ot) {
            int o = 16*ot + l15;
            f32x4 acc = {0.f, 0.f, 0.f, 0.f};
            bf16x8 bf0 = *(const bf16x8*)(smem + 49152 + o*128 + ((0 + l4) ^ keyw)*16);
            bf16x8 bf1 = *(const bf16x8*)(smem + 49152 + o*128 + ((4 + l4) ^ keyw)*16);
            acc = __builtin_amdgcn_mfma_f32_16x16x32_bf16(af0, bf0, acc, 0, 0, 0);
            acc = __builtin_amdgcn_mfma_f32_16x16x32_bf16(af1, bf1, acc, 0, 0, 0);
            short4v pk;
            pk[0] = f2bf(acc[0] + bia[ot]); pk[1] = f2bf(acc[1] + bia[ot]);
            pk[2] = f2bf(acc[2] + bia[ot]); pk[3] = f2bf(acc[3] + bia[ot]);
            int po = pob ^ (o & 7);
            *(short4v*)(smem + 16384 + o*256 + po*16 + (m0 & 7)*2) = pk;
        }
    }
    lgkm_barrier();

    // ---------------- per-relation loop ----------------
    f32x4 tot[4] = {{0,0,0,0},{0,0,0,0},{0,0,0,0},{0,0,0,0}};

    #pragma unroll 1
    for (int r = 0; r < 2; ++r) {
        const size_t aoff = ((size_t)(b*2 + r)*128 + t) * 16384;
        const float* gA = Ag + aoff;
        float*       gO = outg + XOUT_ELEMS + aoff;   // fused exact A-copy

        // ---- P2: stage d[m]*(A+I) -> shAT + exact NT copy + in-register rowsums ----
        {
            float vv[2][4][4];
            #pragma unroll
            for (int k = 0; k < 2; ++k)
                #pragma unroll
                for (int i = 0; i < 4; ++i) {
                    int m = 16*w + 8*k + 4*g + i;
                    f32x4 v = *(const f32x4*)(gA + m*128 + 4*h);   // PLAIN load
                    __builtin_nontemporal_store(v, (f32x4*)(gO + m*128 + 4*h));
                    vv[k][i][0] = v[0]; vv[k][i][1] = v[1];
                    vv[k][i][2] = v[2]; vv[k][i][3] = v[3];
                }
            #pragma unroll
            for (int k = 0; k < 2; ++k)
                #pragma unroll
                for (int i = 0; i < 4; ++i) {
                    float s = vv[k][i][0] + vv[k][i][1] + vv[k][i][2] + vv[k][i][3];
                    s += __shfl_xor(s, 16); s += __shfl_xor(s, 8);
                    s += __shfl_xor(s, 4);  s += __shfl_xor(s, 2); s += __shfl_xor(s, 1);
                    float dv = rsqrtf(1.0f + s);
                    if (h == 4*w + 2*k + g) vv[k][i][i] += 1.0f;   // += I at col m
                    vv[k][i][0] *= dv; vv[k][i][1] *= dv;
                    vv[k][i][2] *= dv; vv[k][i][3] *= dv;
                    if (h == 0) dd[16*w + 8*k + 4*g + i] = dv;
                }
            #pragma unroll
            for (int k = 0; k < 2; ++k) {
                int po = (2*w + k) ^ (h & 7);           // m-oct = 2w+k
                #pragma unroll
                for (int e = 0; e < 4; ++e) {
                    int n = 4*h + e;
                    short4v pk;
                    pk[0] = f2bf(vv[k][0][e]); pk[1] = f2bf(vv[k][1][e]);
                    pk[2] = f2bf(vv[k][2][e]); pk[3] = f2bf(vv[k][3][e]);
                    *(short4v*)(smem + 49152 + n*256 + po*16 + 8*g) = pk;
                }
            }
        }
        lgkm_barrier();

        // ---- P4: GEMM2  D[c][n] = sum_m y[64r+c][m] * (d[m]A~[m][n]), tot += d[n]*D ----
        {
            f32x4 acc[4] = {{0,0,0,0},{0,0,0,0},{0,0,0,0},{0,0,0,0}};
            const int n    = 16*w + l15;
            const int keyA = (n >> 2) & 7;
            #pragma unroll
            for (int s = 0; s < 4; ++s) {
                int octk = 4*s + l4;
                bf16x8 bfr = *(const bf16x8*)(smem + 49152 + n*256 + (octk ^ keyA)*16);
                #pragma unroll
                for (int ct = 0; ct < 4; ++ct) {
                    int o  = 64*r + 16*ct + l15;
                    bf16x8 afr = *(const bf16x8*)(smem + 16384 + o*256 + (octk ^ (o & 7))*16);
                    acc[ct] = __builtin_amdgcn_mfma_f32_16x16x32_bf16(afr, bfr, acc[ct], 0, 0, 0);
                }
            }
            float dn = dd[n];
            #pragma unroll
            for (int ct = 0; ct < 4; ++ct)
                #pragma unroll
                for (int j = 0; j < 4; ++j) tot[ct][j] += acc[ct][j] * dn;
        }
        lgkm_barrier();   // before next r overwrites shAT/dd
    }

    // ---------------- epilogue: x_out[b, c, t, n], NT stores ----------------
    #pragma unroll
    for (int ct = 0; ct < 4; ++ct)
        #pragma unroll
        for (int j = 0; j < 4; ++j) {
            int c = 16*ct + 4*l4 + j;
            int n = 16*w + l15;
            __builtin_nontemporal_store(tot[ct][j],
                &outg[((size_t)(b*64 + c)*128 + t)*128 + n]);
        }
}

extern "C" void kernel_launch(void* const* d_in, const int* in_sizes, int n_in,
                              void* d_out, int out_size, void* d_ws, size_t ws_size,
                              hipStream_t stream) {
    const float* x    = (const float*)d_in[0];
    const float* A    = (const float*)d_in[1];
    const float* W    = (const float*)d_in[2];
    const float* bias = (const float*)d_in[3];
    float* out = (float*)d_out;

    dim3 grid(32 * 128);   // one block per (b, t)
    dim3 block(TB);
    hipLaunchKernelGGL(gcn_fused, grid, block, 0, stream, x, A, W, bias, out);
}

// Round 10
// 232.392 us; speedup vs baseline: 1.0594x; 1.0594x over previous
//
#include <hip/hip_runtime.h>
#include <hip/hip_bf16.h>

#define TB 512

// B=32, R=2, T=128, N=128, C_IN=64, C_OUT=64
constexpr size_t XOUT_ELEMS = 32ull * 64 * 128 * 128;  // 33,554,432

typedef short bf16x8  __attribute__((ext_vector_type(8)));
typedef short short4v __attribute__((ext_vector_type(4)));
typedef float f32x4   __attribute__((ext_vector_type(4)));

static __device__ __forceinline__ short f2bf(float f) {
    __hip_bfloat16 hb = __float2bfloat16(f);           // RNE
    return *reinterpret_cast<short*>(&hb);
}

// lgkm-only barrier: publishes LDS writes/reads without draining vmcnt
// (measured neutral vs __syncthreads in R8, kept as harmless).
static __device__ __forceinline__ void lgkm_barrier() {
    asm volatile("s_waitcnt lgkmcnt(0)" ::: "memory");
    __builtin_amdgcn_s_barrier();
    asm volatile("" ::: "memory");
}

// LDS byte map (81920 B = 2 blocks/CU of the 160 KiB pool):
//  [0,16384)      shXT: x^T bf16, row n stride 128B; elem (n,c): n*128 + po*16 + (c&7)*2,
//                 po = (c>>3) ^ ((n>>2)&7).   Dead after P1; [0,512) reused as dd[128] f32.
//  [16384,49152)  yt: y[o][m] bf16 (read-only after P1), row o stride 256B;
//                 elem: 16384 + o*256 + po*16 + (m&7)*2, po = (m>>3) ^ (o&7)
//  [49152,81920)  P0/P1: shW bf16 [o][c], row o stride 128B; elem: o*128 + po*16 + (c&7)*2,
//                 po = (c>>3) ^ (o&7).
//                 Relation loop: shAT = d[m]*(A+I)[m][n] bf16 transposed (row n, col m);
//                 elem: 49152 + n*256 + po*16 + (m&7)*2, po = (m>>3) ^ ((n>>2)&7)

__global__ __launch_bounds__(TB, 4)
void gcn_fused(const float* __restrict__ xg, const float* __restrict__ Ag,
               const float* __restrict__ Wg, const float* __restrict__ bg,
               float* __restrict__ outg)
{
    __shared__ float4 smem4[5120];
    char*  smem = (char*)smem4;
    float* dd   = (float*)smem;   // d[m] per relation

    const int tid = threadIdx.x;
    const int w   = tid >> 6;     // wave 0..7
    const int l   = tid & 63;
    const int g   = l >> 5;
    const int h   = l & 31;
    const int l15 = l & 15;
    const int l4  = l >> 4;       // 0..3

    const int blk = blockIdx.x;
    const int b = blk >> 7, t = blk & 127;

    // ---------------- P0a: stage x^T (bf16, swizzled), NT loads ----------------
    {
        float vv[4][4];
        #pragma unroll
        for (int i = 0; i < 4; ++i) {
            int c = 8*w + 4*g + i;
            f32x4 v = __builtin_nontemporal_load(
                (const f32x4*)(xg + ((size_t)(b*64 + c)*128 + t)*128 + 4*h));
            vv[i][0] = v[0]; vv[i][1] = v[1]; vv[i][2] = v[2]; vv[i][3] = v[3];
        }
        int po = w ^ (h & 7);                       // c-oct = w ; key = (n>>2)&7 = h&7
        #pragma unroll
        for (int e = 0; e < 4; ++e) {
            int n = 4*h + e;
            short4v pk;
            pk[0] = f2bf(vv[0][e]); pk[1] = f2bf(vv[1][e]);
            pk[2] = f2bf(vv[2][e]); pk[3] = f2bf(vv[3][e]);
            *(short4v*)(smem + n*128 + po*16 + 8*g) = pk;
        }
    }
    // ---------------- P0b: stage W -> shW bf16 (coalesced, cached loads) ----------------
    #pragma unroll
    for (int k2 = 0; k2 < 4; ++k2) {
        int q = tid + TB*k2;                        // < 2048 float4 chunks of W
        f32x4 v = ((const f32x4*)Wg)[q];
        int o = q >> 4, oct = (q >> 1) & 7, hf = q & 1;
        short4v pk;
        pk[0] = f2bf(v[0]); pk[1] = f2bf(v[1]); pk[2] = f2bf(v[2]); pk[3] = f2bf(v[3]);
        *(short4v*)(smem + 49152 + o*128 + (oct ^ (o & 7))*16 + hf*8) = pk;
    }
    // ---------------- P0c: bias per D-column (o = 16*ot + l15) ----------------
    float bia[8];
    #pragma unroll
    for (int ot = 0; ot < 8; ++ot) bia[ot] = bg[16*ot + l15];
    lgkm_barrier();

    // ---------------- P1: GEMM1, swapped operands: D[n][o] = xT·W^T ----------------
    // A-op = xT rows n (loop-invariant!), B-op = W rows o. Lane holds col o = 16ot+l15,
    // rows n = 16w + 4*l4 + j -> 4 consecutive m at fixed o -> packed b64 yt writes.
    {
        const int n    = 16*w + l15;
        const int keyx = (n >> 2) & 7;
        bf16x8 af0 = *(const bf16x8*)(smem + n*128 + ((0 + l4) ^ keyx)*16);
        bf16x8 af1 = *(const bf16x8*)(smem + n*128 + ((4 + l4) ^ keyx)*16);
        const int m0   = 16*w + 4*l4;               // D row base (m = n-axis of yt)
        const int pob  = m0 >> 3;                   // = 2w + (l4>>1)
        const int keyw = l15 & 7;                   // o & 7
        #pragma unroll
        for (int ot = 0; ot < 8; ++ot) {
            int o = 16*ot + l15;
            f32x4 acc = {0.f, 0.f, 0.f, 0.f};
            bf16x8 bf0 = *(const bf16x8*)(smem + 49152 + o*128 + ((0 + l4) ^ keyw)*16);
            bf16x8 bf1 = *(const bf16x8*)(smem + 49152 + o*128 + ((4 + l4) ^ keyw)*16);
            acc = __builtin_amdgcn_mfma_f32_16x16x32_bf16(af0, bf0, acc, 0, 0, 0);
            acc = __builtin_amdgcn_mfma_f32_16x16x32_bf16(af1, bf1, acc, 0, 0, 0);
            short4v pk;
            pk[0] = f2bf(acc[0] + bia[ot]); pk[1] = f2bf(acc[1] + bia[ot]);
            pk[2] = f2bf(acc[2] + bia[ot]); pk[3] = f2bf(acc[3] + bia[ot]);
            int po = pob ^ (o & 7);
            *(short4v*)(smem + 16384 + o*256 + po*16 + (m0 & 7)*2) = pk;
        }
    }
    lgkm_barrier();

    // ---------------- per-relation loop ----------------
    f32x4 tot[4] = {{0,0,0,0},{0,0,0,0},{0,0,0,0},{0,0,0,0}};

    #pragma unroll 1
    for (int r = 0; r < 2; ++r) {
        const size_t aoff = ((size_t)(b*2 + r)*128 + t) * 16384;
        const float* gA = Ag + aoff;
        float*       gO = outg + XOUT_ELEMS + aoff;   // fused exact A-copy

        // ---- P2: stage d[m]*(A+I) -> shAT + exact NT copy + in-register rowsums ----
        {
            float vv[2][4][4];
            #pragma unroll
            for (int k = 0; k < 2; ++k)
                #pragma unroll
                for (int i = 0; i < 4; ++i) {
                    int m = 16*w + 8*k + 4*g + i;
                    f32x4 v = __builtin_nontemporal_load((const f32x4*)(gA + m*128 + 4*h));
                    __builtin_nontemporal_store(v, (f32x4*)(gO + m*128 + 4*h));
                    vv[k][i][0] = v[0]; vv[k][i][1] = v[1];
                    vv[k][i][2] = v[2]; vv[k][i][3] = v[3];
                }
            #pragma unroll
            for (int k = 0; k < 2; ++k)
                #pragma unroll
                for (int i = 0; i < 4; ++i) {
                    float s = vv[k][i][0] + vv[k][i][1] + vv[k][i][2] + vv[k][i][3];
                    s += __shfl_xor(s, 16); s += __shfl_xor(s, 8);
                    s += __shfl_xor(s, 4);  s += __shfl_xor(s, 2); s += __shfl_xor(s, 1);
                    float dv = rsqrtf(1.0f + s);
                    if (h == 4*w + 2*k + g) vv[k][i][i] += 1.0f;   // += I at col m
                    vv[k][i][0] *= dv; vv[k][i][1] *= dv;
                    vv[k][i][2] *= dv; vv[k][i][3] *= dv;
                    if (h == 0) dd[16*w + 8*k + 4*g + i] = dv;
                }
            #pragma unroll
            for (int k = 0; k < 2; ++k) {
                int po = (2*w + k) ^ (h & 7);           // m-oct = 2w+k
                #pragma unroll
                for (int e = 0; e < 4; ++e) {
                    int n = 4*h + e;
                    short4v pk;
                    pk[0] = f2bf(vv[k][0][e]); pk[1] = f2bf(vv[k][1][e]);
                    pk[2] = f2bf(vv[k][2][e]); pk[3] = f2bf(vv[k][3][e]);
                    *(short4v*)(smem + 49152 + n*256 + po*16 + 8*g) = pk;
                }
            }
        }
        lgkm_barrier();

        // ---- P4: GEMM2  D[c][n] = sum_m y[64r+c][m] * (d[m]A~[m][n]), tot += d[n]*D ----
        {
            f32x4 acc[4] = {{0,0,0,0},{0,0,0,0},{0,0,0,0},{0,0,0,0}};
            const int n    = 16*w + l15;
            const int keyA = (n >> 2) & 7;
            #pragma unroll
            for (int s = 0; s < 4; ++s) {
                int octk = 4*s + l4;
                bf16x8 bfr = *(const bf16x8*)(smem + 49152 + n*256 + (octk ^ keyA)*16);
                #pragma unroll
                for (int ct = 0; ct < 4; ++ct) {
                    int o  = 64*r + 16*ct + l15;
                    bf16x8 afr = *(const bf16x8*)(smem + 16384 + o*256 + (octk ^ (o & 7))*16);
                    acc[ct] = __builtin_amdgcn_mfma_f32_16x16x32_bf16(afr, bfr, acc[ct], 0, 0, 0);
                }
            }
            float dn = dd[n];
            #pragma unroll
            for (int ct = 0; ct < 4; ++ct)
                #pragma unroll
                for (int j = 0; j < 4; ++j) tot[ct][j] += acc[ct][j] * dn;
        }
        lgkm_barrier();   // before next r overwrites shAT/dd
    }

    // ---------------- epilogue: x_out[b, c, t, n], NT stores ----------------
    #pragma unroll
    for (int ct = 0; ct < 4; ++ct)
        #pragma unroll
        for (int j = 0; j < 4; ++j) {
            int c = 16*ct + 4*l4 + j;
            int n = 16*w + l15;
            __builtin_nontemporal_store(tot[ct][j],
                &outg[((size_t)(b*64 + c)*128 + t)*128 + n]);
        }
}

extern "C" void kernel_launch(void* const* d_in, const int* in_sizes, int n_in,
                              void* d_out, int out_size, void* d_ws, size_t ws_size,
                              hipStream_t stream) {
    const float* x    = (const float*)d_in[0];
    const float* A    = (const float*)d_in[1];
    const float* W    = (const float*)d_in[2];
    const float* bias = (const float*)d_in[3];
    float* out = (float*)d_out;

    dim3 grid(32 * 128);   // one block per (b, t)
    dim3 block(TB);
    hipLaunchKernelGGL(gcn_fused, grid, block, 0, stream, x, A, W, bias, out);
}